// Round 2
// baseline (101801.959 us; speedup 1.0000x reference)
//
#include <hip/hip_runtime.h>

// Round 1 retry: identical to round 0 submission (container infra failure, no
// kernel signal). See analysis — kernel re-audited for hang/LDS/barrier issues.

typedef unsigned int u32;
typedef unsigned short u16;

#define STEPS 4096

// ---------------- helpers ----------------

__device__ __forceinline__ u16 f2bf(float f) {
  u32 u = __builtin_bit_cast(u32, f);
  u32 r = (u + 0x7fffu + ((u >> 16) & 1u)) >> 16;   // RNE
  return (u16)r;
}
__device__ __forceinline__ float bflo(u32 u) { return __builtin_bit_cast(float, u << 16); }
__device__ __forceinline__ float bfhi(u32 u) { return __builtin_bit_cast(float, u & 0xffff0000u); }
__device__ __forceinline__ float sigmf(float x) { return 1.0f / (1.0f + expf(-x)); }

// 8 MACs: one uint4 of 8 bf16 weights against two float4 of the v-vector
#define MV8(w, va, vb, p)                                                 \
  do {                                                                    \
    p = fmaf(bflo((w).x), (va).x, p); p = fmaf(bfhi((w).x), (va).y, p);   \
    p = fmaf(bflo((w).y), (va).z, p); p = fmaf(bfhi((w).y), (va).w, p);   \
    p = fmaf(bflo((w).z), (vb).x, p); p = fmaf(bfhi((w).z), (vb).y, p);   \
    p = fmaf(bflo((w).w), (vb).z, p); p = fmaf(bfhi((w).w), (vb).w, p);   \
  } while (0)

#define SWZ(j) (((j) ^ ((j) >> 4)) & 15)

// ---------------- GEMM: C[m][n] = sum_k A[m][k]*B[n][k] (+bias[n]) ----------------
// A: M x K row-major (lda), B: N x K row-major (ldb). M,N multiples of 64, K of 16.
__global__ __launch_bounds__(256) void k_gemm_nt(
    const float* __restrict__ A, int lda,
    const float* __restrict__ B, int ldb,
    const float* __restrict__ bias,
    float* __restrict__ C, int ldc, int K)
{
  __shared__ float As[64][17];
  __shared__ float Bs[64][17];
  const int tx = threadIdx.x, ty = threadIdx.y;
  const int tid = ty * 16 + tx;
  const int row0 = blockIdx.y * 64, col0 = blockIdx.x * 64;
  const int lr = tid >> 2, lk = (tid & 3) << 2;
  float acc[4][4] = {};
  for (int kb = 0; kb < K; kb += 16) {
    float4 av = *(const float4*)(A + (size_t)(row0 + lr) * lda + kb + lk);
    float4 bv = *(const float4*)(B + (size_t)(col0 + lr) * ldb + kb + lk);
    As[lr][lk + 0] = av.x; As[lr][lk + 1] = av.y; As[lr][lk + 2] = av.z; As[lr][lk + 3] = av.w;
    Bs[lr][lk + 0] = bv.x; Bs[lr][lk + 1] = bv.y; Bs[lr][lk + 2] = bv.z; Bs[lr][lk + 3] = bv.w;
    __syncthreads();
    #pragma unroll
    for (int kk = 0; kk < 16; ++kk) {
      float a0 = As[ty * 4 + 0][kk], a1 = As[ty * 4 + 1][kk],
            a2 = As[ty * 4 + 2][kk], a3 = As[ty * 4 + 3][kk];
      float b0 = Bs[tx * 4 + 0][kk], b1 = Bs[tx * 4 + 1][kk],
            b2 = Bs[tx * 4 + 2][kk], b3 = Bs[tx * 4 + 3][kk];
      acc[0][0] += a0 * b0; acc[0][1] += a0 * b1; acc[0][2] += a0 * b2; acc[0][3] += a0 * b3;
      acc[1][0] += a1 * b0; acc[1][1] += a1 * b1; acc[1][2] += a1 * b2; acc[1][3] += a1 * b3;
      acc[2][0] += a2 * b0; acc[2][1] += a2 * b1; acc[2][2] += a2 * b2; acc[2][3] += a2 * b3;
      acc[3][0] += a3 * b0; acc[3][1] += a3 * b1; acc[3][2] += a3 * b2; acc[3][3] += a3 * b3;
    }
    __syncthreads();
  }
  #pragma unroll
  for (int i = 0; i < 4; ++i) {
    #pragma unroll
    for (int j = 0; j < 4; ++j) {
      int r = row0 + ty * 4 + i, c = col0 + tx * 4 + j;
      float bv = bias ? bias[c] : 0.0f;
      C[(size_t)r * ldc + c] = acc[i][j] + bv;
    }
  }
}

// ---------------- GEMM: C[m][n] = sum_k A[m][k]*B[k][n] ----------------
// A: M x K row-major (lda), B: K x N row-major (ldb).
__global__ __launch_bounds__(256) void k_gemm_nn(
    const float* __restrict__ A, int lda,
    const float* __restrict__ B, int ldb,
    float* __restrict__ C, int ldc, int K)
{
  __shared__ float As[64][17];
  __shared__ float Bs[16][64];
  const int tx = threadIdx.x, ty = threadIdx.y;
  const int tid = ty * 16 + tx;
  const int row0 = blockIdx.y * 64, col0 = blockIdx.x * 64;
  const int lr = tid >> 2, lk = (tid & 3) << 2;
  const int br = tid >> 4, bn = (tid & 15) << 2;
  float acc[4][4] = {};
  for (int kb = 0; kb < K; kb += 16) {
    float4 av = *(const float4*)(A + (size_t)(row0 + lr) * lda + kb + lk);
    float4 bv = *(const float4*)(B + (size_t)(kb + br) * ldb + col0 + bn);
    As[lr][lk + 0] = av.x; As[lr][lk + 1] = av.y; As[lr][lk + 2] = av.z; As[lr][lk + 3] = av.w;
    Bs[br][bn + 0] = bv.x; Bs[br][bn + 1] = bv.y; Bs[br][bn + 2] = bv.z; Bs[br][bn + 3] = bv.w;
    __syncthreads();
    #pragma unroll
    for (int kk = 0; kk < 16; ++kk) {
      float a0 = As[ty * 4 + 0][kk], a1 = As[ty * 4 + 1][kk],
            a2 = As[ty * 4 + 2][kk], a3 = As[ty * 4 + 3][kk];
      float b0 = Bs[kk][tx * 4 + 0], b1 = Bs[kk][tx * 4 + 1],
            b2 = Bs[kk][tx * 4 + 2], b3 = Bs[kk][tx * 4 + 3];
      acc[0][0] += a0 * b0; acc[0][1] += a0 * b1; acc[0][2] += a0 * b2; acc[0][3] += a0 * b3;
      acc[1][0] += a1 * b0; acc[1][1] += a1 * b1; acc[1][2] += a1 * b2; acc[1][3] += a1 * b3;
      acc[2][0] += a2 * b0; acc[2][1] += a2 * b1; acc[2][2] += a2 * b2; acc[2][3] += a2 * b3;
      acc[3][0] += a3 * b0; acc[3][1] += a3 * b1; acc[3][2] += a3 * b2; acc[3][3] += a3 * b3;
    }
    __syncthreads();
  }
  #pragma unroll
  for (int i = 0; i < 4; ++i)
    #pragma unroll
    for (int j = 0; j < 4; ++j)
      C[(size_t)(row0 + ty * 4 + i) * ldc + col0 + tx * 4 + j] = acc[i][j];
}

// ---------------- weight prep (fp32 -> bf16) ----------------

__global__ void k_prep_big(const float* __restrict__ s0, const float* __restrict__ s1,
                           const float* __restrict__ s2, const float* __restrict__ s3,
                           const float* __restrict__ s4, u16* __restrict__ out)
{
  int i = blockIdx.x * 256 + threadIdx.x;
  if (i >= 5 * 65536) return;
  int m = i >> 16, r = i & 65535;
  const float* s = (m == 0) ? s0 : (m == 1) ? s1 : (m == 2) ? s2 : (m == 3) ? s3 : s4;
  out[i] = f2bf(s[r]);
}

__global__ void k_prep_wih0(const float* __restrict__ in, u16* __restrict__ out) {
  int i = blockIdx.x * 256 + threadIdx.x;
  if (i >= 512 * 16) return;
  int r = i >> 4, k = i & 15;
  out[i] = (k < 12) ? f2bf(in[r * 12 + k]) : (u16)0;
}

__global__ void k_prep_wx(const float* __restrict__ Wi2h, u16* __restrict__ out) {
  int i = blockIdx.x * 256 + threadIdx.x;
  if (i >= 128 * 128) return;
  int r = i >> 7, k = i & 127;
  out[i] = f2bf(Wi2h[r * 1152 + 1024 + k]);
}

__global__ void k_cvt(const float* __restrict__ in, u16* __restrict__ out, int n) {
  int i = blockIdx.x * 256 + threadIdx.x;
  if (i < n) out[i] = f2bf(in[i]);
}

__global__ void k_bcomb(const float* __restrict__ Wi2h, const float* __restrict__ b_s2i,
                        const float* __restrict__ b_i2h, float* __restrict__ bcomb) {
  int i = threadIdx.x;  // 128
  float s = b_i2h[i];
  for (int e = 0; e < 1024; ++e) s = fmaf(Wi2h[i * 1152 + e], b_s2i[e], s);
  bcomb[i] = s;
}

// ---------------- persistent scan: one workgroup, 1024 threads ----------------

__global__ __launch_bounds__(1024, 1) void k_scan(
    const u16* __restrict__ wBig,   // [5][512*128] bf16: Whh0,Wih1,Whh1,Wih2,Whh2
    const u16* __restrict__ wWih0,  // [512*16] (cols 12..15 zero)
    const u16* __restrict__ wWx,    // [128*128]  W_i2h[:,1024:]
    const u16* __restrict__ wWhhf,  // [128*128]  W_h2h
    const u16* __restrict__ wWho,   // [12*128]   W_h2o
    const float* __restrict__ ffe,  // [4096*128] e-part of FF pre-act (incl. b_i2h)
    const float* __restrict__ output0,
    const float* __restrict__ h0,
    const float* __restrict__ c0,
    const float* __restrict__ bih0, const float* __restrict__ bhh0,
    const float* __restrict__ bih1, const float* __restrict__ bhh1,
    const float* __restrict__ bih2, const float* __restrict__ bhh2,
    const float* __restrict__ b_h2h, const float* __restrict__ b_h2o,
    float* __restrict__ out)
{
  __shared__ __align__(16) u16 sWhh0[512 * 128];  // 128 KiB, chunk-swizzled
  __shared__ __align__(16) u16 sWih0[512 * 16];
  __shared__ __align__(16) u16 sWho[12 * 128];
  __shared__ __align__(16) float sh[3][128];
  __shared__ __align__(16) float sc[3][128];
  __shared__ __align__(16) float hidf[128];
  __shared__ __align__(16) float xof[16];
  __shared__ __align__(16) float part[1024];

  const int tid = threadIdx.x;

  // ---- init: stage resident weights + state ----
  {
    const uint4* src = (const uint4*)wBig;  // first 8192 uint4 = Whh0
    uint4* dst = (uint4*)sWhh0;
    for (int idx = tid; idx < 8192; idx += 1024) {
      int j = idx >> 4, q = idx & 15;
      dst[(j << 4) | (q ^ SWZ(j))] = src[idx];  // bank-conflict swizzle
    }
    ((uint4*)sWih0)[tid] = ((const uint4*)wWih0)[tid];  // 1024 uint4 exactly
    if (tid < 192) ((uint4*)sWho)[tid] = ((const uint4*)wWho)[tid];
    if (tid < 384) {
      ((float*)sh)[tid] = h0[tid];
      ((float*)sc)[tid] = c0[tid];
    }
    if (tid < 16) xof[tid] = (tid < 12) ? output0[tid] : 0.0f;
  }

  // preload combined gate biases into registers (act threads only)
  float bg[3][4];
  float bh2h_r = 0.0f, bh2o_r = 0.0f;
  if (tid < 128) {
    #pragma unroll
    for (int l = 0; l < 3; ++l) {
      const float* bi = (l == 0) ? bih0 : (l == 1) ? bih1 : bih2;
      const float* bh = (l == 0) ? bhh0 : (l == 1) ? bhh1 : bhh2;
      #pragma unroll
      for (int gq = 0; gq < 4; ++gq)
        bg[l][gq] = bi[gq * 128 + tid] + bh[gq * 128 + tid];
    }
    bh2h_r = b_h2h[tid];
    if (tid < 12) bh2o_r = b_h2o[tid];
  }
  __syncthreads();

  #pragma unroll 1
  for (int t = 0; t < STEPS; ++t) {
    // ======== LSTM layer 0: gates = Wih0@o_prev + Whh0@h0_prev ========
    {
      const int j = tid & 511;
      float p = 0.0f;
      if (tid < 512) {  // ih half: K=16 (padded), LDS-resident
        const uint4* wr = (const uint4*)sWih0 + (j << 1);
        const float4* vr = (const float4*)xof;
        #pragma unroll
        for (int q = 0; q < 2; ++q) {
          uint4 w = wr[q]; float4 va = vr[2 * q], vb = vr[2 * q + 1];
          MV8(w, va, vb, p);
        }
      } else {          // hh half: K=128, LDS-resident (swizzled)
        const uint4* sW = (const uint4*)sWhh0;
        const float4* vr = (const float4*)&sh[0][0];
        const int base = j << 4, sw = SWZ(j);
        #pragma unroll
        for (int q = 0; q < 16; ++q) {
          uint4 w = sW[base | (q ^ sw)];
          float4 va = vr[2 * q], vb = vr[2 * q + 1];
          MV8(w, va, vb, p);
        }
      }
      part[tid] = p;
    }
    __syncthreads();
    if (tid < 128) {
      float gi = part[tid]       + part[512 + tid] + bg[0][0];
      float gf = part[128 + tid] + part[640 + tid] + bg[0][1];
      float gg = part[256 + tid] + part[768 + tid] + bg[0][2];
      float go = part[384 + tid] + part[896 + tid] + bg[0][3];
      float cn = sigmf(gf) * sc[0][tid] + sigmf(gi) * tanhf(gg);
      sc[0][tid] = cn;
      sh[0][tid] = sigmf(go) * tanhf(cn);
    }
    __syncthreads();

    // ======== LSTM layers 1, 2 (weights streamed from L2) ========
    #pragma unroll
    for (int l = 1; l <= 2; ++l) {
      {
        const int j = tid & 511;
        const u16* W = wBig + (size_t)(2 * l - (tid < 512 ? 1 : 0)) * 65536;
        const float4* vr = (tid < 512) ? (const float4*)&sh[l - 1][0]
                                       : (const float4*)&sh[l][0];
        const uint4* wr = (const uint4*)(W + (j << 7));
        float p = 0.0f;
        #pragma unroll
        for (int q = 0; q < 16; ++q) {
          uint4 w = wr[q]; float4 va = vr[2 * q], vb = vr[2 * q + 1];
          MV8(w, va, vb, p);
        }
        part[tid] = p;
      }
      __syncthreads();
      if (tid < 128) {
        float gi = part[tid]       + part[512 + tid] + bg[l][0];
        float gf = part[128 + tid] + part[640 + tid] + bg[l][1];
        float gg = part[256 + tid] + part[768 + tid] + bg[l][2];
        float go = part[384 + tid] + part[896 + tid] + bg[l][3];
        float cn = sigmf(gf) * sc[l][tid] + sigmf(gi) * tanhf(gg);
        sc[l][tid] = cn;
        sh[l][tid] = sigmf(go) * tanhf(cn);
      }
      __syncthreads();
    }

    // ======== FF1: hid = tanh(ffe[t] + Wx @ h2) ========
    {
      const int i = tid >> 3, s = tid & 7;
      const uint4* wr = (const uint4*)(wWx + (i << 7) + (s << 4));
      const float4* vr = (const float4*)&sh[2][s << 4];
      float p = 0.0f;
      #pragma unroll
      for (int q = 0; q < 2; ++q) {
        uint4 w = wr[q]; float4 va = vr[2 * q], vb = vr[2 * q + 1];
        MV8(w, va, vb, p);
      }
      part[tid] = p;
    }
    __syncthreads();
    if (tid < 128) {
      float s8 = 0.0f;
      #pragma unroll
      for (int q = 0; q < 8; ++q) s8 += part[(tid << 3) + q];
      hidf[tid] = tanhf(s8 + ffe[((size_t)t << 7) + tid]);
    }
    __syncthreads();

    // ======== FF2, FF3: hid = relu(W_h2h @ hid + b_h2h) ========
    #pragma unroll
    for (int r = 0; r < 2; ++r) {
      {
        const int i = tid >> 3, s = tid & 7;
        const uint4* wr = (const uint4*)(wWhhf + (i << 7) + (s << 4));
        const float4* vr = (const float4*)&hidf[s << 4];
        float p = 0.0f;
        #pragma unroll
        for (int q = 0; q < 2; ++q) {
          uint4 w = wr[q]; float4 va = vr[2 * q], vb = vr[2 * q + 1];
          MV8(w, va, vb, p);
        }
        part[tid] = p;
      }
      __syncthreads();
      if (tid < 128) {
        float s8 = 0.0f;
        #pragma unroll
        for (int q = 0; q < 8; ++q) s8 += part[(tid << 3) + q];
        hidf[tid] = fmaxf(s8 + bh2h_r, 0.0f);
      }
      __syncthreads();
    }

    // ======== output: o = sigmoid(W_h2o @ hid + b_h2o) ========
    if (tid < 96) {
      const int i = tid >> 3, s = tid & 7;
      const uint4* wr = (const uint4*)(sWho + (i << 7) + (s << 4));
      const float4* vr = (const float4*)&hidf[s << 4];
      float p = 0.0f;
      #pragma unroll
      for (int q = 0; q < 2; ++q) {
        uint4 w = wr[q]; float4 va = vr[2 * q], vb = vr[2 * q + 1];
        MV8(w, va, vb, p);
      }
      part[tid] = p;
    }
    __syncthreads();
    if (tid < 12) {
      float s8 = 0.0f;
      #pragma unroll
      for (int q = 0; q < 8; ++q) s8 += part[(tid << 3) + q];
      float o = sigmf(s8 + bh2o_r);
      out[(size_t)t * 12 + tid] = o;
      xof[tid] = o;
    }
    __syncthreads();
  }

  // final hN, cN
  if (tid < 384) {
    out[49152 + tid] = ((const float*)sh)[tid];
    out[49536 + tid] = ((const float*)sc)[tid];
  }
}

// ---------------- launch ----------------

extern "C" void kernel_launch(void* const* d_in, const int* in_sizes, int n_in,
                              void* d_out, int out_size, void* d_ws, size_t ws_size,
                              hipStream_t stream)
{
  (void)in_sizes; (void)n_in; (void)out_size; (void)ws_size;

  const float* inputs  = (const float*)d_in[0];
  const float* output0 = (const float*)d_in[1];
  const float* h0      = (const float*)d_in[2];
  const float* c0      = (const float*)d_in[3];
  const float* W_s2i   = (const float*)d_in[4];
  const float* b_s2i   = (const float*)d_in[5];
  const float* W_i2h   = (const float*)d_in[6];
  const float* b_i2h   = (const float*)d_in[7];
  const float* W_h2h   = (const float*)d_in[8];
  const float* b_h2h   = (const float*)d_in[9];
  const float* W_h2o   = (const float*)d_in[10];
  const float* b_h2o   = (const float*)d_in[11];
  const float* Wih0    = (const float*)d_in[12];
  const float* Whh0    = (const float*)d_in[13];
  const float* bih0    = (const float*)d_in[14];
  const float* bhh0    = (const float*)d_in[15];
  const float* Wih1    = (const float*)d_in[16];
  const float* Whh1    = (const float*)d_in[17];
  const float* bih1    = (const float*)d_in[18];
  const float* bhh1    = (const float*)d_in[19];
  const float* Wih2    = (const float*)d_in[20];
  const float* Whh2    = (const float*)d_in[21];
  const float* bih2    = (const float*)d_in[22];
  const float* bhh2    = (const float*)d_in[23];

  char* ws = (char*)d_ws;
  float* wcomb = (float*)(ws + 0);           // 128*8192*4 = 4,194,304
  float* bcomb = (float*)(ws + 4194304);     // 512
  float* ffe   = (float*)(ws + 4195328);     // 4096*128*4 = 2,097,152
  u16* wBig    = (u16*)(ws + 6292480);       // 5*65536*2 = 655,360
  u16* wWih0   = (u16*)(ws + 6947840);       // 16,384
  u16* wWx     = (u16*)(ws + 6964224);       // 32,768
  u16* wWhhf   = (u16*)(ws + 6996992);       // 32,768
  u16* wWho    = (u16*)(ws + 7029760);       // 3,072   (total ~6.7 MB)

  dim3 blk(16, 16);

  // Wcomb = W_i2h[:, :1024] @ W_s2i   (128 x 8192)
  k_gemm_nn<<<dim3(8192 / 64, 128 / 64), blk, 0, stream>>>(
      W_i2h, 1152, W_s2i, 8192, wcomb, 8192, 1024);
  // bcomb = W_i2h[:, :1024] @ b_s2i + b_i2h
  k_bcomb<<<dim3(1), dim3(128), 0, stream>>>(W_i2h, b_s2i, b_i2h, bcomb);
  // ffe = inputs @ Wcomb.T + bcomb    (4096 x 128)
  k_gemm_nt<<<dim3(128 / 64, 4096 / 64), blk, 0, stream>>>(
      inputs, 8192, wcomb, 8192, bcomb, ffe, 128, 8192);

  // weight conversions
  k_prep_big<<<dim3((5 * 65536 + 255) / 256), dim3(256), 0, stream>>>(
      Whh0, Wih1, Whh1, Wih2, Whh2, wBig);
  k_prep_wih0<<<dim3(8192 / 256), dim3(256), 0, stream>>>(Wih0, wWih0);
  k_prep_wx<<<dim3(16384 / 256), dim3(256), 0, stream>>>(W_i2h, wWx);
  k_cvt<<<dim3(16384 / 256), dim3(256), 0, stream>>>(W_h2h, wWhhf, 16384);
  k_cvt<<<dim3(6), dim3(256), 0, stream>>>(W_h2o, wWho, 1536);

  // persistent sequential scan
  k_scan<<<dim3(1), dim3(1024), 0, stream>>>(
      wBig, wWih0, wWx, wWhhf, wWho, ffe,
      output0, h0, c0,
      bih0, bhh0, bih1, bhh1, bih2, bhh2,
      b_h2h, b_h2o, (float*)d_out);
}

// Round 3
// 60785.437 us; speedup vs baseline: 1.6748x; 1.6748x over previous
//
#include <hip/hip_runtime.h>

typedef unsigned int u32;
typedef unsigned short u16;

#define STEPS 4096

// ---------------- helpers ----------------

__device__ __forceinline__ u16 f2bf(float f) {
  u32 u = __builtin_bit_cast(u32, f);
  u32 r = (u + 0x7fffu + ((u >> 16) & 1u)) >> 16;   // RNE
  return (u16)r;
}
__device__ __forceinline__ float bflo(u32 u) { return __builtin_bit_cast(float, u << 16); }
__device__ __forceinline__ float bfhi(u32 u) { return __builtin_bit_cast(float, u & 0xffff0000u); }
__device__ __forceinline__ float sigmf(float x) { return 1.0f / (1.0f + expf(-x)); }

// 2-way bf16 dot with f32 accumulate; hardware v_dot2_f32_bf16 when available
#if defined(__has_builtin)
#if __has_builtin(__builtin_amdgcn_fdot2_f32_bf16)
#define HAVE_DOT2_BF16 1
#endif
#endif

#ifdef HAVE_DOT2_BF16
typedef __bf16 bf16x2 __attribute__((ext_vector_type(2)));
__device__ __forceinline__ float dot2bf(u32 a, u32 b, float acc) {
  return __builtin_amdgcn_fdot2_f32_bf16(__builtin_bit_cast(bf16x2, a),
                                         __builtin_bit_cast(bf16x2, b), acc, false);
}
#else
__device__ __forceinline__ float dot2bf(u32 a, u32 b, float acc) {
  acc = fmaf(bflo(a), bflo(b), acc);
  acc = fmaf(bfhi(a), bfhi(b), acc);
  return acc;
}
#endif

__device__ __forceinline__ float dot8(uint4 w, uint4 v, float acc) {
  acc = dot2bf(w.x, v.x, acc); acc = dot2bf(w.y, v.y, acc);
  acc = dot2bf(w.z, v.z, acc); acc = dot2bf(w.w, v.w, acc);
  return acc;
}

// ---------------- GEMM: C[m][n] = sum_k A[m][k]*B[n][k] (+bias[n]) ----------------
__global__ __launch_bounds__(256) void k_gemm_nt(
    const float* __restrict__ A, int lda,
    const float* __restrict__ B, int ldb,
    const float* __restrict__ bias,
    float* __restrict__ C, int ldc, int K)
{
  __shared__ float As[64][17];
  __shared__ float Bs[64][17];
  const int tx = threadIdx.x, ty = threadIdx.y;
  const int tid = ty * 16 + tx;
  const int row0 = blockIdx.y * 64, col0 = blockIdx.x * 64;
  const int lr = tid >> 2, lk = (tid & 3) << 2;
  float acc[4][4] = {};
  for (int kb = 0; kb < K; kb += 16) {
    float4 av = *(const float4*)(A + (size_t)(row0 + lr) * lda + kb + lk);
    float4 bv = *(const float4*)(B + (size_t)(col0 + lr) * ldb + kb + lk);
    As[lr][lk + 0] = av.x; As[lr][lk + 1] = av.y; As[lr][lk + 2] = av.z; As[lr][lk + 3] = av.w;
    Bs[lr][lk + 0] = bv.x; Bs[lr][lk + 1] = bv.y; Bs[lr][lk + 2] = bv.z; Bs[lr][lk + 3] = bv.w;
    __syncthreads();
    #pragma unroll
    for (int kk = 0; kk < 16; ++kk) {
      float a0 = As[ty * 4 + 0][kk], a1 = As[ty * 4 + 1][kk],
            a2 = As[ty * 4 + 2][kk], a3 = As[ty * 4 + 3][kk];
      float b0 = Bs[tx * 4 + 0][kk], b1 = Bs[tx * 4 + 1][kk],
            b2 = Bs[tx * 4 + 2][kk], b3 = Bs[tx * 4 + 3][kk];
      acc[0][0] += a0 * b0; acc[0][1] += a0 * b1; acc[0][2] += a0 * b2; acc[0][3] += a0 * b3;
      acc[1][0] += a1 * b0; acc[1][1] += a1 * b1; acc[1][2] += a1 * b2; acc[1][3] += a1 * b3;
      acc[2][0] += a2 * b0; acc[2][1] += a2 * b1; acc[2][2] += a2 * b2; acc[2][3] += a2 * b3;
      acc[3][0] += a3 * b0; acc[3][1] += a3 * b1; acc[3][2] += a3 * b2; acc[3][3] += a3 * b3;
    }
    __syncthreads();
  }
  #pragma unroll
  for (int i = 0; i < 4; ++i) {
    #pragma unroll
    for (int j = 0; j < 4; ++j) {
      int r = row0 + ty * 4 + i, c = col0 + tx * 4 + j;
      float bv = bias ? bias[c] : 0.0f;
      C[(size_t)r * ldc + c] = acc[i][j] + bv;
    }
  }
}

// ---------------- GEMM: C[m][n] = sum_k A[m][k]*B[k][n] ----------------
__global__ __launch_bounds__(256) void k_gemm_nn(
    const float* __restrict__ A, int lda,
    const float* __restrict__ B, int ldb,
    float* __restrict__ C, int ldc, int K)
{
  __shared__ float As[64][17];
  __shared__ float Bs[16][64];
  const int tx = threadIdx.x, ty = threadIdx.y;
  const int tid = ty * 16 + tx;
  const int row0 = blockIdx.y * 64, col0 = blockIdx.x * 64;
  const int lr = tid >> 2, lk = (tid & 3) << 2;
  const int br = tid >> 4, bn = (tid & 15) << 2;
  float acc[4][4] = {};
  for (int kb = 0; kb < K; kb += 16) {
    float4 av = *(const float4*)(A + (size_t)(row0 + lr) * lda + kb + lk);
    float4 bv = *(const float4*)(B + (size_t)(kb + br) * ldb + col0 + bn);
    As[lr][lk + 0] = av.x; As[lr][lk + 1] = av.y; As[lr][lk + 2] = av.z; As[lr][lk + 3] = av.w;
    Bs[br][bn + 0] = bv.x; Bs[br][bn + 1] = bv.y; Bs[br][bn + 2] = bv.z; Bs[br][bn + 3] = bv.w;
    __syncthreads();
    #pragma unroll
    for (int kk = 0; kk < 16; ++kk) {
      float a0 = As[ty * 4 + 0][kk], a1 = As[ty * 4 + 1][kk],
            a2 = As[ty * 4 + 2][kk], a3 = As[ty * 4 + 3][kk];
      float b0 = Bs[kk][tx * 4 + 0], b1 = Bs[kk][tx * 4 + 1],
            b2 = Bs[kk][tx * 4 + 2], b3 = Bs[kk][tx * 4 + 3];
      acc[0][0] += a0 * b0; acc[0][1] += a0 * b1; acc[0][2] += a0 * b2; acc[0][3] += a0 * b3;
      acc[1][0] += a1 * b0; acc[1][1] += a1 * b1; acc[1][2] += a1 * b2; acc[1][3] += a1 * b3;
      acc[2][0] += a2 * b0; acc[2][1] += a2 * b1; acc[2][2] += a2 * b2; acc[2][3] += a2 * b3;
      acc[3][0] += a3 * b0; acc[3][1] += a3 * b1; acc[3][2] += a3 * b2; acc[3][3] += a3 * b3;
    }
    __syncthreads();
  }
  #pragma unroll
  for (int i = 0; i < 4; ++i)
    #pragma unroll
    for (int j = 0; j < 4; ++j)
      C[(size_t)(row0 + ty * 4 + i) * ldc + col0 + tx * 4 + j] = acc[i][j];
}

__global__ void k_bcomb(const float* __restrict__ Wi2h, const float* __restrict__ b_s2i,
                        const float* __restrict__ b_i2h, float* __restrict__ bcomb) {
  int i = threadIdx.x;  // 128
  float s = b_i2h[i];
  for (int e = 0; e < 1024; ++e) s = fmaf(Wi2h[i * 1152 + e], b_s2i[e], s);
  bcomb[i] = s;
}

// ---------------- weight prep ----------------
// Whh0 "LDS image": uint4 img[r*16 + (q8 ^ swz(r))] = row r, chunk q8
// swz(r) = (r&7) ^ ((r>>7)<<1)  -> bank-optimal (4-way floor) for group-mapped reads
__global__ void k_prep_whh0img(const float* __restrict__ W, u16* __restrict__ out) {
  int idx = blockIdx.x * 256 + threadIdx.x;
  if (idx >= 65536) return;
  int e = idx & 7, q8 = (idx >> 3) & 15, r = idx >> 7;
  int swz = (r & 7) ^ ((r >> 7) << 1);
  out[(r * 16 + (q8 ^ swz)) * 8 + e] = f2bf(W[r * 128 + q8 * 8 + e]);
}

// layers 1,2 -> coalesced-per-q8 layout: out[l*131072 + q8*8192 + lane*8 + e]
// lane=(i,s): q=s>>1, half=s&1, r=q*128+i, col=q8*8+e; src = half?Whh:Wih
__global__ void k_prep_wL(const float* __restrict__ Wih1, const float* __restrict__ Whh1,
                          const float* __restrict__ Wih2, const float* __restrict__ Whh2,
                          u16* __restrict__ out) {
  int idx = blockIdx.x * 256 + threadIdx.x;
  if (idx >= 262144) return;
  int e = idx & 7, lane = (idx >> 3) & 1023, q8 = (idx >> 13) & 15, l = idx >> 17;
  int i = lane >> 3, s = lane & 7, q = s >> 1, half = s & 1;
  int r = q * 128 + i, col = q8 * 8 + e;
  const float* src = (l == 0) ? (half ? Whh1 : Wih1) : (half ? Whh2 : Wih2);
  out[idx] = f2bf(src[r * 128 + col]);
}

// small consts: gWih0 (512x16, cols>=12 zero), gWx, gWf (per-lane 16-col slices), gWo
__global__ void k_prep_smalls(const float* __restrict__ Wih0, const float* __restrict__ W_i2h,
                              const float* __restrict__ W_h2h, const float* __restrict__ W_h2o,
                              u16* __restrict__ gWih0, u16* __restrict__ gWx,
                              u16* __restrict__ gWf, u16* __restrict__ gWo) {
  int idx = blockIdx.x * 256 + threadIdx.x;
  if (idx < 8192) {                     // gWih0[r*16+col]
    int col = idx & 15, r = idx >> 4;
    gWih0[idx] = (col < 12) ? f2bf(Wih0[r * 12 + col]) : (u16)0;
  } else if (idx < 24576) {             // gWx[lane*16+c]
    int k = idx - 8192, c = k & 15, lane = k >> 4;
    int i = lane >> 3, s = lane & 7;
    gWx[k] = f2bf(W_i2h[i * 1152 + 1024 + s * 16 + c]);
  } else if (idx < 40960) {             // gWf[lane*16+c]
    int k = idx - 24576, c = k & 15, lane = k >> 4;
    int i = lane >> 3, s = lane & 7;
    gWf[k] = f2bf(W_h2h[i * 128 + s * 16 + c]);
  } else if (idx < 42496) {             // gWo[lane*16+c], 96 lanes
    int k = idx - 40960, c = k & 15, lane = k >> 4;
    int i = lane >> 3, s = lane & 7;
    gWo[k] = f2bf(W_h2o[i * 128 + s * 16 + c]);
  }
}

// ---------------- persistent scan ----------------
// 1024 threads = 128 groups x 8 lanes. Group i owns h-index i; lane s in group:
// gate q=s>>1, K-half (s&1): 0 = x-input (Wih / prev-layer h), 1 = own-h (Whh).
// Reductions via __shfl_xor inside the 8-lane group -> 7 barriers/step.

#define LSTM_ACT(CR, HN, DST)                                              \
  p += __shfl_xor(p, 1);                                                   \
  {                                                                        \
    float gf = __shfl_xor(p, 2), gg = __shfl_xor(p, 4), go = __shfl_xor(p, 6); \
    if (lead) {                                                            \
      float cn = sigmf(gf) * (CR) + sigmf(p) * tanhf(gg);                  \
      (CR) = cn; (HN) = sigmf(go) * tanhf(cn);                             \
      (DST) = f2bf(HN);                                                    \
    }                                                                      \
  }

#define FF_RED() do { p += __shfl_xor(p, 1); p += __shfl_xor(p, 2); p += __shfl_xor(p, 4); } while (0)

__global__ __launch_bounds__(1024, 4) void k_scan(
    const uint4* __restrict__ gWhh0img, const uint4* __restrict__ gWih0,
    const uint4* __restrict__ wL,       const uint4* __restrict__ gWx,
    const uint4* __restrict__ gWf,      const uint4* __restrict__ gWo,
    const float* __restrict__ ffe,
    const float* __restrict__ output0, const float* __restrict__ h0,
    const float* __restrict__ c0,
    const float* __restrict__ bih0, const float* __restrict__ bhh0,
    const float* __restrict__ bih1, const float* __restrict__ bhh1,
    const float* __restrict__ bih2, const float* __restrict__ bhh2,
    const float* __restrict__ b_h2h, const float* __restrict__ b_h2o,
    float* __restrict__ out)
{
  __shared__ __align__(16) uint4 sWhh0[8192];     // 128 KiB, swizzled image
  __shared__ __align__(16) u16 sh16[2][3][128];   // ping-pong h (bf16)
  __shared__ __align__(16) u16 hidA[128];
  __shared__ __align__(16) u16 hidB[128];
  __shared__ __align__(16) u16 xof16[16];
  __shared__ __align__(16) uint4 sWho[192];       // 3 KiB
  __shared__ float outbuf[3072];                  // 12 KiB (256 steps x 12)

  const int tid = threadIdx.x;
  const int i = tid >> 3, s = tid & 7, q = s >> 1;
  const bool odd = (s & 1) != 0, lead = (s == 0);

  // ---- stage LDS ----
  #pragma unroll
  for (int k2 = 0; k2 < 8; ++k2) sWhh0[k2 * 1024 + tid] = gWhh0img[k2 * 1024 + tid];
  if (tid < 192) sWho[tid] = gWo[tid];
  if (tid < 384) ((u16*)sh16)[384 + tid] = f2bf(h0[tid]);   // sh16[1][*][*]
  if (tid < 16) xof16[tid] = (tid < 12) ? f2bf(output0[tid]) : (u16)0;

  // ---- per-lane constant registers ----
  uint4 wih0a = {}, wih0b = {};
  float bg0 = 0.f, bg1 = 0.f, bg2 = 0.f;
  if (!odd) {
    const int r = q * 128 + i;
    wih0a = gWih0[r * 2]; wih0b = gWih0[r * 2 + 1];
    bg0 = bih0[r] + bhh0[r]; bg1 = bih1[r] + bhh1[r]; bg2 = bih2[r] + bhh2[r];
  }
  const uint4 wxa = gWx[tid * 2], wxb = gWx[tid * 2 + 1];
  const uint4 wfa = gWf[tid * 2], wfb = gWf[tid * 2 + 1];
  float bh2h_r = 0.f, bh2o_r = 0.f;
  float cr0 = 0.f, cr1 = 0.f, cr2 = 0.f, hn0 = 0.f, hn1 = 0.f, hn2 = 0.f;
  if (lead) {
    bh2h_r = b_h2h[i];
    if (i < 12) bh2o_r = b_h2o[i];
    cr0 = c0[i]; cr1 = c0[128 + i]; cr2 = c0[256 + i];
    hn0 = h0[i]; hn1 = h0[128 + i]; hn2 = h0[256 + i];
  }

  // ---- layer-1 weights: register-resident for the whole scan (64 VGPRs) ----
  uint4 w1[16];
  #pragma unroll
  for (int k2 = 0; k2 < 16; ++k2) w1[k2] = wL[k2 * 1024 + tid];
  const uint4* __restrict__ wL2 = wL + 16384;

  const int sw0 = (i & 7) ^ (q << 1);
  const int wbase0 = (q * 128 + i) * 16;

  __syncthreads();

  #pragma unroll 1
  for (int t = 0; t < STEPS; ++t) {
    const int cur = t & 1, prv = cur ^ 1;
    float fe = 0.f;
    if (lead) fe = ffe[t * 128 + i];    // consumed 4 phases later

    // ======== L0: gates = Wih0@o_prev (even lanes) + Whh0@h0_prev (odd) ========
    float p;
    if (!odd) {
      const uint4* xv = (const uint4*)xof16;
      p = dot8(wih0a, xv[0], bg0);
      p = dot8(wih0b, xv[1], p);
    } else {
      p = 0.f;
      const uint4* vv = (const uint4*)&sh16[prv][0][0];
      #pragma unroll
      for (int k2 = 0; k2 < 16; ++k2)
        p = dot8(sWhh0[wbase0 + (k2 ^ sw0)], vv[k2], p);
    }
    LSTM_ACT(cr0, hn0, sh16[cur][0][i])
    __syncthreads();                                   // bar1

    // ======== L1: weights in registers ========
    {
      const uint4* vv = odd ? (const uint4*)&sh16[prv][1][0]
                            : (const uint4*)&sh16[cur][0][0];
      p = odd ? 0.f : bg1;
      #pragma unroll
      for (int k2 = 0; k2 < 16; ++k2) p = dot8(w1[k2], vv[k2], p);
    }
    LSTM_ACT(cr1, hn1, sh16[cur][1][i])
    __syncthreads();                                   // bar2

    // ======== L2: weights streamed from L2$ with 4-deep rolling window ========
    {
      const uint4* vv = odd ? (const uint4*)&sh16[prv][2][0]
                            : (const uint4*)&sh16[cur][1][0];
      p = odd ? 0.f : bg2;
      const uint4* pw = wL2 + tid;
      uint4 wa = pw[0], wb = pw[1024], wc = pw[2048], wd = pw[3072];
      #pragma unroll
      for (int k2 = 0; k2 < 16; k2 += 4) {
        uint4 na = {}, nb = {}, nc = {}, nd = {};
        if (k2 + 4 < 16) {
          na = pw[(k2 + 4) * 1024]; nb = pw[(k2 + 5) * 1024];
          nc = pw[(k2 + 6) * 1024]; nd = pw[(k2 + 7) * 1024];
        }
        p = dot8(wa, vv[k2], p);     p = dot8(wb, vv[k2 + 1], p);
        p = dot8(wc, vv[k2 + 2], p); p = dot8(wd, vv[k2 + 3], p);
        wa = na; wb = nb; wc = nc; wd = nd;
      }
    }
    LSTM_ACT(cr2, hn2, sh16[cur][2][i])
    __syncthreads();                                   // bar3

    // ======== FF1: hid = tanh(ffe[t] + Wx @ h2) ========
    {
      const uint4* vv = (const uint4*)&sh16[cur][2][0];
      p = dot8(wxa, vv[s * 2], 0.f);
      p = dot8(wxb, vv[s * 2 + 1], p);
      FF_RED();
      if (lead) hidA[i] = f2bf(tanhf(p + fe));
    }
    __syncthreads();                                   // bar4

    // ======== FF2: relu(W_h2h @ hid + b) ========
    {
      const uint4* vv = (const uint4*)hidA;
      p = dot8(wfa, vv[s * 2], 0.f);
      p = dot8(wfb, vv[s * 2 + 1], p);
      FF_RED();
      if (lead) hidB[i] = f2bf(fmaxf(p + bh2h_r, 0.f));
    }
    __syncthreads();                                   // bar5

    // ======== FF3: relu(W_h2h @ hid + b) ========
    {
      const uint4* vv = (const uint4*)hidB;
      p = dot8(wfa, vv[s * 2], 0.f);
      p = dot8(wfb, vv[s * 2 + 1], p);
      FF_RED();
      if (lead) hidA[i] = f2bf(fmaxf(p + bh2h_r, 0.f));
    }
    __syncthreads();                                   // bar6

    // ======== OUT: o = sigmoid(W_h2o @ hid + b) ========
    if (tid < 96) {
      const uint4* vv = (const uint4*)hidA;
      p = dot8(sWho[tid * 2], vv[s * 2], 0.f);
      p = dot8(sWho[tid * 2 + 1], vv[s * 2 + 1], p);
      FF_RED();
      if (lead) {
        float o = sigmf(p + bh2o_r);
        outbuf[(t & 255) * 12 + i] = o;
        xof16[i] = f2bf(o);
      }
    }
    __syncthreads();                                   // bar7

    if ((t & 255) == 255) {                            // coalesced flush, 1/256 steps
      const int b0 = (t - 255) * 12;
      #pragma unroll
      for (int k2 = 0; k2 < 3; ++k2)
        out[b0 + k2 * 1024 + tid] = outbuf[k2 * 1024 + tid];
    }
  }

  // final hN (fp32-tracked), cN (fp32 registers)
  if (lead) {
    out[49152 + i] = hn0; out[49152 + 128 + i] = hn1; out[49152 + 256 + i] = hn2;
    out[49536 + i] = cr0; out[49536 + 128 + i] = cr1; out[49536 + 256 + i] = cr2;
  }
}

// ---------------- launch ----------------

extern "C" void kernel_launch(void* const* d_in, const int* in_sizes, int n_in,
                              void* d_out, int out_size, void* d_ws, size_t ws_size,
                              hipStream_t stream)
{
  (void)in_sizes; (void)n_in; (void)out_size; (void)ws_size;

  const float* inputs  = (const float*)d_in[0];
  const float* output0 = (const float*)d_in[1];
  const float* h0      = (const float*)d_in[2];
  const float* c0      = (const float*)d_in[3];
  const float* W_s2i   = (const float*)d_in[4];
  const float* b_s2i   = (const float*)d_in[5];
  const float* W_i2h   = (const float*)d_in[6];
  const float* b_i2h   = (const float*)d_in[7];
  const float* W_h2h   = (const float*)d_in[8];
  const float* b_h2o_f = (const float*)d_in[11];
  const float* b_h2h_f = (const float*)d_in[9];
  const float* W_h2o   = (const float*)d_in[10];
  const float* Wih0    = (const float*)d_in[12];
  const float* Whh0    = (const float*)d_in[13];
  const float* bih0    = (const float*)d_in[14];
  const float* bhh0    = (const float*)d_in[15];
  const float* Wih1    = (const float*)d_in[16];
  const float* Whh1    = (const float*)d_in[17];
  const float* bih1    = (const float*)d_in[18];
  const float* bhh1    = (const float*)d_in[19];
  const float* Wih2    = (const float*)d_in[20];
  const float* Whh2    = (const float*)d_in[21];
  const float* bih2    = (const float*)d_in[22];
  const float* bhh2    = (const float*)d_in[23];

  char* ws = (char*)d_ws;
  float* wcomb   = (float*)(ws + 0);           // 4,194,304
  float* bcomb   = (float*)(ws + 4194304);     // 1,024 (512 used)
  float* ffe     = (float*)(ws + 4195328);     // 2,097,152 -> 6,292,480
  u16* gWhh0img  = (u16*)(ws + 6292480);       // 131,072 -> 6,423,552
  u16* wL        = (u16*)(ws + 6423552);       // 524,288 -> 6,947,840
  u16* gWih0     = (u16*)(ws + 6947840);       // 16,384  -> 6,964,224
  u16* gWx       = (u16*)(ws + 6964224);       // 32,768  -> 6,996,992
  u16* gWf       = (u16*)(ws + 6996992);       // 32,768  -> 7,029,760
  u16* gWo       = (u16*)(ws + 7029760);       // 3,072   -> 7,032,832

  dim3 blk(16, 16);

  // ffe = inputs @ (W_i2h[:, :1024] @ W_s2i).T + (W_i2h[:, :1024]@b_s2i + b_i2h)
  k_gemm_nn<<<dim3(8192 / 64, 128 / 64), blk, 0, stream>>>(
      W_i2h, 1152, W_s2i, 8192, wcomb, 8192, 1024);
  k_bcomb<<<dim3(1), dim3(128), 0, stream>>>(W_i2h, b_s2i, b_i2h, bcomb);
  k_gemm_nt<<<dim3(128 / 64, 4096 / 64), blk, 0, stream>>>(
      inputs, 8192, wcomb, 8192, bcomb, ffe, 128, 8192);

  // weight prep
  k_prep_whh0img<<<dim3(256), dim3(256), 0, stream>>>(Whh0, gWhh0img);
  k_prep_wL<<<dim3(1024), dim3(256), 0, stream>>>(Wih1, Whh1, Wih2, Whh2, wL);
  k_prep_smalls<<<dim3(166), dim3(256), 0, stream>>>(
      Wih0, W_i2h, W_h2h, W_h2o, gWih0, gWx, gWf, gWo);

  // persistent sequential scan
  k_scan<<<dim3(1), dim3(1024), 0, stream>>>(
      (const uint4*)gWhh0img, (const uint4*)gWih0, (const uint4*)wL,
      (const uint4*)gWx, (const uint4*)gWf, (const uint4*)gWo,
      ffe, output0, h0, c0,
      bih0, bhh0, bih1, bhh1, bih2, bhh2,
      b_h2h_f, b_h2o_f, (float*)d_out);
}